// Round 1
// baseline (1546.560 us; speedup 1.0000x reference)
//
#include <hip/hip_runtime.h>
#include <math.h>

#define CDIV(a,b) (((a)+(b)-1)/(b))
#define WPC 16   // workgroups per cell for the conv kernel (64 cells * 16 = 1024 wgs)

__device__ __forceinline__ float elu_f(float x){ return x > 0.f ? x : expm1f(x); }

// ---------------- basis + cell histogram + degree ----------------
__global__ void k_basis(const float* __restrict__ ea, const int* __restrict__ dst,
                        float* __restrict__ basis, int* __restrict__ cellid,
                        int* __restrict__ cellcnt, int* __restrict__ deg, int E)
{
    int e = blockIdx.x * blockDim.x + threadIdx.x;
    if (e >= E) return;
    float f[3]; int bi[3];
    #pragma unroll
    for (int d = 0; d < 3; d++) {
        float v = ea[e*3+d] * 4.f;      // K-1 = 4
        float b = floorf(v);
        f[d] = v - b;
        int bb = (int)b; bb = bb < 0 ? 0 : (bb > 3 ? 3 : bb);
        bi[d] = bb;
    }
    int cell = bi[0] + 4*bi[1] + 16*bi[2];
    cellid[e] = cell;
    atomicAdd(cellcnt + cell, 1);
    atomicAdd(deg + dst[e], 1);
    #pragma unroll
    for (int c = 0; c < 8; c++) {
        float bs = 1.f;
        #pragma unroll
        for (int d = 0; d < 3; d++)
            bs *= ((c>>d)&1) ? f[d] : (1.f - f[d]);
        basis[e*8+c] = bs;
    }
}

__global__ void k_scan(const int* __restrict__ cnt, int* __restrict__ start, int* __restrict__ fill)
{
    if (threadIdx.x == 0 && blockIdx.x == 0) {
        int s = 0;
        for (int i = 0; i < 64; i++) { start[i] = s; fill[i] = s; s += cnt[i]; }
        start[64] = s;
    }
}

__global__ void k_scatter(const int* __restrict__ cellid, int* __restrict__ fill,
                          int* __restrict__ elist, int E)
{
    int e = blockIdx.x * blockDim.x + threadIdx.x;
    if (e >= E) return;
    int pos = atomicAdd(fill + cellid[e], 1);
    elist[pos] = e;
}

__global__ void k_invdeg(const int* __restrict__ deg, float* __restrict__ invdeg, int N)
{
    int n = blockIdx.x * blockDim.x + threadIdx.x;
    if (n < N) invdeg[n] = 1.f / fmaxf((float)deg[n], 1.f);
}

// ---------------- spline conv scatter (cell-grouped) ----------------
// grid = 64 cells * WPC, block = 256 (4 waves). Each wave owns a 16-edge chunk.
// Per chunk: y[e][o] = sum_c b[e][c] * sum_i x[src_e][i] * W[kc[c]][i][o]
__global__ __launch_bounds__(256) void k_conv(
    const float* __restrict__ xin, const float* __restrict__ Wg,
    const int* __restrict__ elist, const int* __restrict__ cellstart,
    const float* __restrict__ basis, const int* __restrict__ src,
    const int* __restrict__ dst, float* __restrict__ accum)
{
    __shared__ float xst[4][64][16];   // [wave][i][e]
    __shared__ float bt[4][8][16];     // [wave][corner][e]
    __shared__ int   dstw[4][16];

    const int cell = blockIdx.x / WPC;
    const int sub  = blockIdx.x % WPC;
    const int w    = threadIdx.x >> 6;
    const int lane = threadIdx.x & 63;

    int kc[8];
    {
        int b0 = cell & 3, b1 = (cell >> 2) & 3, b2 = (cell >> 4) & 3;
        #pragma unroll
        for (int c = 0; c < 8; c++)
            kc[c] = (b0 + (c&1)) + 5*(b1 + ((c>>1)&1)) + 25*(b2 + ((c>>2)&1));
    }
    const int s0 = cellstart[cell], s1 = cellstart[cell+1];

    const int eg = lane >> 4;   // 0..3  -> edges eg*4..eg*4+3
    const int og = lane & 15;   // 0..15 -> channels og*4..og*4+3
    const int se = lane >> 2;   // staging edge 0..15
    const int sm = lane & 3;    // staging quarter

    for (int cb = s0 + sub*64; cb < s1; cb += WPC*64) {
        int base = cb + w*16;
        int ne = s1 - base; ne = ne < 0 ? 0 : (ne > 16 ? 16 : ne);

        if (ne > 0) {
            if (se < ne) {
                int eid = elist[base + se];
                int sn  = src[eid];
                const float4* xr = (const float4*)(xin + (size_t)sn*64);
                #pragma unroll
                for (int j = 0; j < 4; j++) {
                    int m = sm + j*4;
                    float4 v = xr[m];
                    xst[w][m*4+0][se] = v.x;
                    xst[w][m*4+1][se] = v.y;
                    xst[w][m*4+2][se] = v.z;
                    xst[w][m*4+3][se] = v.w;
                }
                if (sm == 0) {
                    const float4* br = (const float4*)(basis + (size_t)eid*8);
                    float4 bA = br[0], bB = br[1];
                    bt[w][0][se]=bA.x; bt[w][1][se]=bA.y; bt[w][2][se]=bA.z; bt[w][3][se]=bA.w;
                    bt[w][4][se]=bB.x; bt[w][5][se]=bB.y; bt[w][6][se]=bB.z; bt[w][7][se]=bB.w;
                    dstw[w][se] = dst[eid];
                }
            } else {
                #pragma unroll
                for (int j = 0; j < 4; j++) {
                    int m = sm + j*4;
                    xst[w][m*4+0][se] = 0.f;
                    xst[w][m*4+1][se] = 0.f;
                    xst[w][m*4+2][se] = 0.f;
                    xst[w][m*4+3][se] = 0.f;
                }
                if (sm == 0) {
                    #pragma unroll
                    for (int c = 0; c < 8; c++) bt[w][c][se] = 0.f;
                    dstw[w][se] = 0;
                }
            }
        }
        __syncthreads();

        if (ne > 0) {
            float y[4][4] = {};
            #pragma unroll
            for (int c = 0; c < 8; c++) {
                const float* Wk = Wg + (size_t)kc[c]*4096;
                float4 b4 = *(const float4*)&bt[w][c][eg*4];
                float t[4][4] = {};
                #pragma unroll 8
                for (int i = 0; i < 64; i++) {
                    float4 w4 = *(const float4*)(Wk + i*64 + og*4);
                    float4 x4 = *(const float4*)&xst[w][i][eg*4];
                    float xa[4] = {x4.x, x4.y, x4.z, x4.w};
                    float wv[4] = {w4.x, w4.y, w4.z, w4.w};
                    #pragma unroll
                    for (int a = 0; a < 4; a++)
                        #pragma unroll
                        for (int b = 0; b < 4; b++)
                            t[a][b] = fmaf(xa[a], wv[b], t[a][b]);
                }
                float ba[4] = {b4.x, b4.y, b4.z, b4.w};
                #pragma unroll
                for (int a = 0; a < 4; a++)
                    #pragma unroll
                    for (int b = 0; b < 4; b++)
                        y[a][b] = fmaf(ba[a], t[a][b], y[a][b]);
            }
            #pragma unroll
            for (int a = 0; a < 4; a++) {
                int dn = dstw[w][eg*4 + a];
                float* ap = accum + (size_t)dn*64 + og*4;
                atomicAdd(ap+0, y[a][0]);
                atomicAdd(ap+1, y[a][1]);
                atomicAdd(ap+2, y[a][2]);
                atomicAdd(ap+3, y[a][3]);
            }
        }
        __syncthreads();
    }
}

// ---------------- finalize: mean + root weight + bias + ELU ----------------
__global__ void k_final(const float* __restrict__ accum, const float* __restrict__ xin,
                        const float* __restrict__ root, const float* __restrict__ bias,
                        const float* __restrict__ invdeg, float* __restrict__ hout, int N)
{
    int n = blockIdx.x;
    int o = threadIdx.x;
    float acc = accum[(size_t)n*64+o] * invdeg[n] + bias[o];
    float xv = xin[(size_t)n*64+o];
    #pragma unroll 8
    for (int i = 0; i < 64; i++)
        acc = fmaf(__shfl(xv, i, 64), root[i*64+o], acc);
    hout[(size_t)n*64+o] = elu_f(acc);
}

// ---------------- pos_x preprocess: offset + squared norm ----------------
__global__ void k_px(const float* __restrict__ posx, const int* __restrict__ bx,
                     float4* __restrict__ px4, int N)
{
    int n = blockIdx.x * blockDim.x + threadIdx.x;
    if (n >= N) return;
    float off = (float)bx[n] * 1e5f;
    float a = posx[n*3+0]+off, b = posx[n*3+1]+off, c = posx[n*3+2]+off;
    px4[n] = make_float4(a, b, c, a*a + b*b + c*c);
}

// ---------------- brute-force 3-NN interpolation ----------------
// block = 256 (4 waves), 8 query points per block (2 per wave).
__global__ __launch_bounds__(256) void k_knn(
    const float* __restrict__ h2, const float4* __restrict__ px4,
    const float* __restrict__ posy, const int* __restrict__ by,
    float* __restrict__ out, int N, int Ny)
{
    __shared__ float4 pxs[2048];
    const int w = threadIdx.x >> 6, lane = threadIdx.x & 63;
    const int ybase = blockIdx.x*8 + w*2;

    float py[2][3], sy[2];
    #pragma unroll
    for (int yy = 0; yy < 2; yy++) {
        int y = ybase + yy;
        float off = (float)by[y] * 1e5f;
        float a = posy[y*3+0]+off, b = posy[y*3+1]+off, c = posy[y*3+2]+off;
        py[yy][0]=a; py[yy][1]=b; py[yy][2]=c; sy[yy] = a*a + b*b + c*c;
    }
    float td[2][3]; int ti[2][3];
    #pragma unroll
    for (int yy = 0; yy < 2; yy++)
        #pragma unroll
        for (int j = 0; j < 3; j++) { td[yy][j] = 3.4e38f; ti[yy][j] = 0x7fffffff; }

    const int nch = N / 2048;
    for (int ch = 0; ch < nch; ch++) {
        #pragma unroll
        for (int r = 0; r < 8; r++)
            pxs[threadIdx.x + r*256] = px4[ch*2048 + threadIdx.x + r*256];
        __syncthreads();
        for (int jj = 0; jj < 32; jj++) {
            float4 p = pxs[jj*64 + lane];
            int gi = ch*2048 + jj*64 + lane;
            #pragma unroll
            for (int yy = 0; yy < 2; yy++) {
                float d2 = sy[yy] + p.w - 2.f*(py[yy][0]*p.x + py[yy][1]*p.y + py[yy][2]*p.z);
                if (d2 < td[yy][2]) {
                    td[yy][2] = d2; ti[yy][2] = gi;
                    if (td[yy][2] < td[yy][1]) {
                        float tf=td[yy][1]; td[yy][1]=td[yy][2]; td[yy][2]=tf;
                        int tt=ti[yy][1]; ti[yy][1]=ti[yy][2]; ti[yy][2]=tt;
                    }
                    if (td[yy][1] < td[yy][0]) {
                        float tf=td[yy][0]; td[yy][0]=td[yy][1]; td[yy][1]=tf;
                        int tt=ti[yy][0]; ti[yy][0]=ti[yy][1]; ti[yy][1]=tt;
                    }
                }
            }
        }
        __syncthreads();
    }

    #pragma unroll
    for (int yy = 0; yy < 2; yy++) {
        int y = ybase + yy;
        float cd = td[yy][0]; int ci = ti[yy][0]; int nxt = 1;
        float rd[3]; int ri[3];
        for (int j = 0; j < 3; j++) {
            float md = cd; int mi = ci;
            #pragma unroll
            for (int s = 1; s < 64; s <<= 1) {
                float od = __shfl_xor(md, s, 64);
                int   oi = __shfl_xor(mi, s, 64);
                if (od < md || (od == md && oi < mi)) { md = od; mi = oi; }
            }
            rd[j] = md; ri[j] = mi;
            if (mi == ci) {
                if (nxt < 3) { cd = td[yy][nxt]; ci = ti[yy][nxt]; nxt++; }
                else { cd = 3.4e38f; ci = 0x7fffffff; }
            }
        }
        float w0 = 1.f/fmaxf(rd[0], 1e-16f);
        float w1 = 1.f/fmaxf(rd[1], 1e-16f);
        float w2 = 1.f/fmaxf(rd[2], 1e-16f);
        float ws = w0 + w1 + w2;
        float v = w0*h2[(size_t)ri[0]*64+lane] + w1*h2[(size_t)ri[1]*64+lane]
                + w2*h2[(size_t)ri[2]*64+lane];
        out[(size_t)y*64+lane] = v / ws;
    }
}

extern "C" void kernel_launch(void* const* d_in, const int* in_sizes, int n_in,
                              void* d_out, int out_size, void* d_ws, size_t ws_size,
                              hipStream_t stream)
{
    const float* x     = (const float*)d_in[0];
    const int*   ei    = (const int*)d_in[1];
    const float* ea    = (const float*)d_in[2];
    const float* posx  = (const float*)d_in[3];
    const int*   bx    = (const int*)d_in[4];
    const float* posy  = (const float*)d_in[5];
    const int*   by    = (const int*)d_in[6];
    const float* Wa    = (const float*)d_in[7];
    const float* roota = (const float*)d_in[8];
    const float* biasa = (const float*)d_in[9];
    const float* Wb    = (const float*)d_in[10];
    const float* rootb = (const float*)d_in[11];
    const float* biasb = (const float*)d_in[12];

    const int N  = in_sizes[0] / 64;
    const int E  = in_sizes[1] / 2;
    const int Ny = in_sizes[5] / 3;
    const int* srcp = ei;
    const int* dstp = ei + E;

    char* ws = (char*)d_ws;
    size_t off = 0;
    auto alloc = [&](size_t bytes) { void* p = ws + off; off += (bytes + 255) & ~255ull; return p; };
    float*  basis    = (float*)alloc((size_t)E*8*4);
    int*    elist    = (int*)  alloc((size_t)E*4);
    int*    cellid   = (int*)  alloc((size_t)E*4);
    int*    deg      = (int*)  alloc((size_t)N*4);
    int*    cellcnt  = (int*)  alloc(64*4);
    int*    cellstart= (int*)  alloc(65*4);
    int*    cellfill = (int*)  alloc(64*4);
    float*  invdeg   = (float*)alloc((size_t)N*4);
    float*  accum    = (float*)alloc((size_t)N*64*4);
    float*  h1       = (float*)alloc((size_t)N*64*4);
    float*  h2       = (float*)alloc((size_t)N*64*4);
    float4* px4      = (float4*)alloc((size_t)N*16);
    (void)ws_size; (void)n_in; (void)out_size;

    hipMemsetAsync(deg, 0, (size_t)N*4, stream);
    hipMemsetAsync(cellcnt, 0, 64*4, stream);

    k_basis  <<<CDIV(E,256), 256, 0, stream>>>(ea, dstp, basis, cellid, cellcnt, deg, E);
    k_scan   <<<1, 64, 0, stream>>>(cellcnt, cellstart, cellfill);
    k_scatter<<<CDIV(E,256), 256, 0, stream>>>(cellid, cellfill, elist, E);
    k_invdeg <<<CDIV(N,256), 256, 0, stream>>>(deg, invdeg, N);
    k_px     <<<CDIV(N,256), 256, 0, stream>>>(posx, bx, px4, N);

    hipMemsetAsync(accum, 0, (size_t)N*64*4, stream);
    k_conv <<<64*WPC, 256, 0, stream>>>(x, Wa, elist, cellstart, basis, srcp, dstp, accum);
    k_final<<<N, 64, 0, stream>>>(accum, x, roota, biasa, invdeg, h1, N);

    hipMemsetAsync(accum, 0, (size_t)N*64*4, stream);
    k_conv <<<64*WPC, 256, 0, stream>>>(h1, Wb, elist, cellstart, basis, srcp, dstp, accum);
    k_final<<<N, 64, 0, stream>>>(accum, h1, rootb, biasb, invdeg, h2, N);

    k_knn<<<Ny/8, 256, 0, stream>>>(h2, px4, posy, by, (float*)d_out, N, Ny);
}

// Round 2
// 615.934 us; speedup vs baseline: 2.5109x; 2.5109x over previous
//
#include <hip/hip_runtime.h>
#include <math.h>

#define CDIV(a,b) (((a)+(b)-1)/(b))
#define WPC2 16   // workgroups per cell for conv (64 cells * 16 = 1024 blocks)
#define KCH 8     // point chunks for knn phase 1

__device__ __forceinline__ float elu_f(float x){ return x > 0.f ? x : expm1f(x); }

// ---------------- basis + cell histogram (LDS-aggregated) + degree ----------------
__global__ void k_basis(const float* __restrict__ ea, const int* __restrict__ dst,
                        float* __restrict__ basis, int* __restrict__ cellid,
                        int* __restrict__ cellcnt, int* __restrict__ deg, int E)
{
    __shared__ int hist[64];
    const int tid = threadIdx.x;
    if (tid < 64) hist[tid] = 0;
    __syncthreads();
    int e = blockIdx.x * blockDim.x + tid;
    if (e < E) {
        float f[3]; int bi[3];
        #pragma unroll
        for (int d = 0; d < 3; d++) {
            float v = ea[e*3+d] * 4.f;      // K-1 = 4
            float b = floorf(v);
            f[d] = v - b;
            int bb = (int)b; bb = bb < 0 ? 0 : (bb > 3 ? 3 : bb);
            bi[d] = bb;
        }
        int cell = bi[0] + 4*bi[1] + 16*bi[2];
        cellid[e] = cell;
        atomicAdd(&hist[cell], 1);
        atomicAdd(deg + dst[e], 1);
        float bs[8];
        #pragma unroll
        for (int c = 0; c < 8; c++) {
            float b = 1.f;
            #pragma unroll
            for (int d = 0; d < 3; d++)
                b *= ((c>>d)&1) ? f[d] : (1.f - f[d]);
            bs[c] = b;
        }
        float4* bw = (float4*)(basis + (size_t)e*8);
        bw[0] = make_float4(bs[0],bs[1],bs[2],bs[3]);
        bw[1] = make_float4(bs[4],bs[5],bs[6],bs[7]);
    }
    __syncthreads();
    if (tid < 64 && hist[tid]) atomicAdd(cellcnt + tid, hist[tid]);
}

__global__ void k_scan(const int* __restrict__ cnt, int* __restrict__ start, int* __restrict__ fill)
{
    if (threadIdx.x == 0 && blockIdx.x == 0) {
        int s = 0;
        for (int i = 0; i < 64; i++) { start[i] = s; fill[i] = s; s += cnt[i]; }
        start[64] = s;
    }
}

__global__ void k_scatter(const int* __restrict__ cellid, int* __restrict__ fill,
                          int* __restrict__ elist, int E)
{
    __shared__ int hist[64], bas[64];
    const int tid = threadIdx.x;
    if (tid < 64) hist[tid] = 0;
    __syncthreads();
    int e = blockIdx.x * blockDim.x + tid;
    int cell = 0, loc = 0;
    bool act = e < E;
    if (act) { cell = cellid[e]; loc = atomicAdd(&hist[cell], 1); }
    __syncthreads();
    if (tid < 64) bas[tid] = hist[tid] ? atomicAdd(fill + tid, hist[tid]) : 0;
    __syncthreads();
    if (act) elist[bas[cell] + loc] = e;
}

__global__ void k_invdeg(const int* __restrict__ deg, float* __restrict__ invdeg, int N)
{
    int n = blockIdx.x * blockDim.x + threadIdx.x;
    if (n < N) invdeg[n] = 1.f / fmaxf((float)deg[n], 1.f);
}

// ---------------- spline conv (cell-grouped, 64-edge blocks, W in LDS) ----------------
// grid = 64 cells * WPC2, block = 256 (4 waves). Block processes 64 edges/chunk.
// Wave w covers out channels [w*16, w*16+16); lane: eg=lane&15 -> edges eg*4..+3,
// og4=lane>>4 -> outs ocol..ocol+3. W corner staged in LDS, double-buffered.
__global__ __launch_bounds__(256) void k_conv(
    const float* __restrict__ xin, const float* __restrict__ Wg,
    const int* __restrict__ elist, const int* __restrict__ cellstart,
    const float* __restrict__ basis, const int* __restrict__ src,
    const int* __restrict__ dst, float* __restrict__ accum)
{
    __shared__ float xst[64][64];      // [in_ch][edge]   16KB
    __shared__ float wbuf[2][64][64];  // [buf][in_ch][out_ch] 32KB
    __shared__ float bts[8][64];       // [corner][edge]  2KB
    __shared__ int   dstw[64];

    const int cell = blockIdx.x / WPC2;
    const int sub  = blockIdx.x % WPC2;
    const int tid  = threadIdx.x;
    const int w    = tid >> 6;
    const int lane = tid & 63;
    const int eg   = lane & 15;
    const int og4  = lane >> 4;
    const int ocol = w*16 + og4*4;

    int kc[8];
    {
        int b0 = cell & 3, b1 = (cell >> 2) & 3, b2 = (cell >> 4) & 3;
        #pragma unroll
        for (int c = 0; c < 8; c++)
            kc[c] = (b0 + (c&1)) + 5*(b1 + ((c>>1)&1)) + 25*(b2 + ((c>>2)&1));
    }
    const int s0 = cellstart[cell], s1 = cellstart[cell+1];
    const int se = tid >> 2, sm = tid & 3;

    for (int base = s0 + sub*64; base < s1; base += WPC2*64) {
        int ne = s1 - base; ne = ne > 64 ? 64 : ne;
        __syncthreads();   // previous chunk's readers of xst/bts/dstw are done
        if (se < ne) {
            int eid = elist[base + se];
            int sn  = src[eid];
            const float4* xr = (const float4*)(xin + (size_t)sn*64);
            #pragma unroll
            for (int j = 0; j < 4; j++) {
                int m = sm + j*4;
                float4 v = xr[m];
                xst[m*4+0][se] = v.x; xst[m*4+1][se] = v.y;
                xst[m*4+2][se] = v.z; xst[m*4+3][se] = v.w;
            }
            if (sm == 0) {
                const float4* br = (const float4*)(basis + (size_t)eid*8);
                float4 bA = br[0], bB = br[1];
                bts[0][se]=bA.x; bts[1][se]=bA.y; bts[2][se]=bA.z; bts[3][se]=bA.w;
                bts[4][se]=bB.x; bts[5][se]=bB.y; bts[6][se]=bB.z; bts[7][se]=bB.w;
                dstw[se] = dst[eid];
            }
        } else {
            #pragma unroll
            for (int j = 0; j < 4; j++) {
                int m = sm + j*4;
                xst[m*4+0][se]=0.f; xst[m*4+1][se]=0.f;
                xst[m*4+2][se]=0.f; xst[m*4+3][se]=0.f;
            }
            if (sm == 0) {
                #pragma unroll
                for (int c = 0; c < 8; c++) bts[c][se]=0.f;
                dstw[se] = 0;
            }
        }
        {   // corner 0 -> wbuf[0]
            const float4* Wk = (const float4*)(Wg + (size_t)kc[0]*4096);
            float4 r0 = Wk[tid], r1 = Wk[tid+256], r2 = Wk[tid+512], r3 = Wk[tid+768];
            float4* wd = (float4*)&wbuf[0][0][0];
            wd[tid]=r0; wd[tid+256]=r1; wd[tid+512]=r2; wd[tid+768]=r3;
        }
        __syncthreads();

        float y[4][4] = {};
        #pragma unroll
        for (int c = 0; c < 8; c++) {
            float4 p0, p1, p2, p3;
            if (c < 7) {   // prefetch next corner into registers
                const float4* Wk = (const float4*)(Wg + (size_t)kc[c+1]*4096);
                p0 = Wk[tid]; p1 = Wk[tid+256]; p2 = Wk[tid+512]; p3 = Wk[tid+768];
            }
            const float (* __restrict__ wc)[64] = wbuf[c & 1];
            float t[4][4] = {};
            #pragma unroll 8
            for (int i = 0; i < 64; i++) {
                float4 x4 = *(const float4*)&xst[i][eg*4];
                float4 w4 = *(const float4*)&wc[i][ocol];
                float xa[4] = {x4.x, x4.y, x4.z, x4.w};
                float wv[4] = {w4.x, w4.y, w4.z, w4.w};
                #pragma unroll
                for (int a = 0; a < 4; a++)
                    #pragma unroll
                    for (int b = 0; b < 4; b++)
                        t[a][b] = fmaf(xa[a], wv[b], t[a][b]);
            }
            float4 b4 = *(const float4*)&bts[c][eg*4];
            float ba[4] = {b4.x, b4.y, b4.z, b4.w};
            #pragma unroll
            for (int a = 0; a < 4; a++)
                #pragma unroll
                for (int b = 0; b < 4; b++)
                    y[a][b] = fmaf(ba[a], t[a][b], y[a][b]);
            if (c < 7) {   // write prefetched corner to the other buffer
                float4* wd = (float4*)&wbuf[(c+1)&1][0][0];
                wd[tid]=p0; wd[tid+256]=p1; wd[tid+512]=p2; wd[tid+768]=p3;
            }
            __syncthreads();
        }
        #pragma unroll
        for (int a = 0; a < 4; a++) {
            int ei = eg*4 + a;
            if (ei < ne) {
                float* ap = accum + (size_t)dstw[ei]*64 + ocol;
                atomicAdd(ap+0, y[a][0]);
                atomicAdd(ap+1, y[a][1]);
                atomicAdd(ap+2, y[a][2]);
                atomicAdd(ap+3, y[a][3]);
            }
        }
    }
}

// ---------------- finalize: mean + root weight + bias + ELU ----------------
__global__ void k_final(const float* __restrict__ accum, const float* __restrict__ xin,
                        const float* __restrict__ root, const float* __restrict__ bias,
                        const float* __restrict__ invdeg, float* __restrict__ hout, int N)
{
    int n = blockIdx.x;
    int o = threadIdx.x;
    float acc = accum[(size_t)n*64+o] * invdeg[n] + bias[o];
    float xv = xin[(size_t)n*64+o];
    #pragma unroll 8
    for (int i = 0; i < 64; i++)
        acc = fmaf(__shfl(xv, i, 64), root[i*64+o], acc);
    hout[(size_t)n*64+o] = elu_f(acc);
}

// ---------------- pos_x preprocess: offset + squared norm ----------------
__global__ void k_px(const float* __restrict__ posx, const int* __restrict__ bx,
                     float4* __restrict__ px4, int N)
{
    int n = blockIdx.x * blockDim.x + threadIdx.x;
    if (n >= N) return;
    float off = (float)bx[n] * 1e5f;
    float a = posx[n*3+0]+off, b = posx[n*3+1]+off, c = posx[n*3+2]+off;
    px4[n] = make_float4(a, b, c, a*a + b*b + c*c);
}

// ---------------- 3-NN phase 1: per (query, point-chunk) partial top-3 ----------------
// block = 256 threads, one query per thread. grid = (Ny/256) * KCH.
__global__ __launch_bounds__(256) void k_knn_part(
    const float4* __restrict__ px4, const float* __restrict__ posy,
    const int* __restrict__ by, float* __restrict__ pd, int* __restrict__ pi,
    int N, int Ny)
{
    __shared__ float4 pxs[1024];
    const int qb  = (blockIdx.x / KCH) * 256;
    const int ch  = blockIdx.x % KCH;
    const int NC  = N / KCH;                 // 1024
    const int tid = threadIdx.x;
    #pragma unroll
    for (int r = 0; r < 4; r++)
        pxs[tid + r*256] = px4[ch*NC + tid + r*256];
    const int q = qb + tid;
    float off = (float)by[q] * 1e5f;
    float qa = posy[q*3+0]+off, qbv = posy[q*3+1]+off, qc = posy[q*3+2]+off;
    float sy = qa*qa + qbv*qbv + qc*qc;
    __syncthreads();

    float td[3] = {3.4e38f, 3.4e38f, 3.4e38f};
    int   ti[3] = {0x7fffffff, 0x7fffffff, 0x7fffffff};
    #pragma unroll 4
    for (int p = 0; p < 1024; p++) {
        float4 pt = pxs[p];                  // uniform address -> broadcast
        float d2 = sy + pt.w - 2.f*(qa*pt.x + qbv*pt.y + qc*pt.z);
        if (d2 < td[2]) {
            int gi = ch*NC + p;
            td[2] = d2; ti[2] = gi;
            if (td[2] < td[1]) { float tf=td[1]; td[1]=td[2]; td[2]=tf; int tt=ti[1]; ti[1]=ti[2]; ti[2]=tt; }
            if (td[1] < td[0]) { float tf=td[0]; td[0]=td[1]; td[1]=tf; int tt=ti[0]; ti[0]=ti[1]; ti[1]=tt; }
        }
    }
    size_t ob = ((size_t)q*KCH + ch)*3;
    pd[ob+0]=td[0]; pd[ob+1]=td[1]; pd[ob+2]=td[2];
    pi[ob+0]=ti[0]; pi[ob+1]=ti[1]; pi[ob+2]=ti[2];
}

// ---------------- 3-NN phase 2: merge 24 candidates + interpolate ----------------
// one wave per query; lanes 0..23 hold candidates, all 64 lanes do the interp.
__global__ __launch_bounds__(256) void k_knn_merge(
    const float* __restrict__ pd, const int* __restrict__ pi,
    const float* __restrict__ h2, float* __restrict__ out, int Ny)
{
    const int w = threadIdx.x >> 6, lane = threadIdx.x & 63;
    const int q = blockIdx.x*4 + w;
    float cd = 3.4e38f; int ci = 0x7fffffff;
    if (lane < 24) { cd = pd[(size_t)q*24 + lane]; ci = pi[(size_t)q*24 + lane]; }
    float rd[3]; int ri[3];
    #pragma unroll
    for (int j = 0; j < 3; j++) {
        float md = cd; int mi = ci;
        #pragma unroll
        for (int s = 1; s < 64; s <<= 1) {
            float od = __shfl_xor(md, s, 64);
            int   oi = __shfl_xor(mi, s, 64);
            if (od < md || (od == md && oi < mi)) { md = od; mi = oi; }
        }
        rd[j] = md; ri[j] = mi;
        if (ci == mi) { cd = 3.4e38f; ci = 0x7fffffff; }   // exclude winner (indices unique)
    }
    float w0 = 1.f/fmaxf(rd[0], 1e-16f);
    float w1 = 1.f/fmaxf(rd[1], 1e-16f);
    float w2 = 1.f/fmaxf(rd[2], 1e-16f);
    float ws = w0 + w1 + w2;
    float v = w0*h2[(size_t)ri[0]*64+lane] + w1*h2[(size_t)ri[1]*64+lane]
            + w2*h2[(size_t)ri[2]*64+lane];
    out[(size_t)q*64+lane] = v / ws;
}

extern "C" void kernel_launch(void* const* d_in, const int* in_sizes, int n_in,
                              void* d_out, int out_size, void* d_ws, size_t ws_size,
                              hipStream_t stream)
{
    const float* x     = (const float*)d_in[0];
    const int*   ei    = (const int*)d_in[1];
    const float* ea    = (const float*)d_in[2];
    const float* posx  = (const float*)d_in[3];
    const int*   bx    = (const int*)d_in[4];
    const float* posy  = (const float*)d_in[5];
    const int*   by    = (const int*)d_in[6];
    const float* Wa    = (const float*)d_in[7];
    const float* roota = (const float*)d_in[8];
    const float* biasa = (const float*)d_in[9];
    const float* Wb    = (const float*)d_in[10];
    const float* rootb = (const float*)d_in[11];
    const float* biasb = (const float*)d_in[12];

    const int N  = in_sizes[0] / 64;
    const int E  = in_sizes[1] / 2;
    const int Ny = in_sizes[5] / 3;
    const int* srcp = ei;
    const int* dstp = ei + E;

    char* ws = (char*)d_ws;
    size_t off = 0;
    auto alloc = [&](size_t bytes) { void* p = ws + off; off += (bytes + 255) & ~255ull; return p; };
    float*  basis    = (float*)alloc((size_t)E*8*4);
    int*    elist    = (int*)  alloc((size_t)E*4);
    int*    cellid   = (int*)  alloc((size_t)E*4);
    int*    deg      = (int*)  alloc((size_t)N*4);
    int*    cellcnt  = (int*)  alloc(64*4);
    int*    cellstart= (int*)  alloc(65*4);
    int*    cellfill = (int*)  alloc(64*4);
    float*  invdeg   = (float*)alloc((size_t)N*4);
    float*  accum    = (float*)alloc((size_t)N*64*4);
    float*  h1       = (float*)alloc((size_t)N*64*4);
    float*  h2       = (float*)alloc((size_t)N*64*4);
    float4* px4      = (float4*)alloc((size_t)N*16);
    float*  pd       = (float*)alloc((size_t)Ny*KCH*3*4);
    int*    pi       = (int*)  alloc((size_t)Ny*KCH*3*4);
    (void)ws_size; (void)n_in; (void)out_size;

    hipMemsetAsync(deg, 0, (size_t)N*4, stream);
    hipMemsetAsync(cellcnt, 0, 64*4, stream);

    k_basis  <<<CDIV(E,256), 256, 0, stream>>>(ea, dstp, basis, cellid, cellcnt, deg, E);
    k_scan   <<<1, 64, 0, stream>>>(cellcnt, cellstart, cellfill);
    k_scatter<<<CDIV(E,256), 256, 0, stream>>>(cellid, cellfill, elist, E);
    k_invdeg <<<CDIV(N,256), 256, 0, stream>>>(deg, invdeg, N);
    k_px     <<<CDIV(N,256), 256, 0, stream>>>(posx, bx, px4, N);

    hipMemsetAsync(accum, 0, (size_t)N*64*4, stream);
    k_conv <<<64*WPC2, 256, 0, stream>>>(x, Wa, elist, cellstart, basis, srcp, dstp, accum);
    k_final<<<N, 64, 0, stream>>>(accum, x, roota, biasa, invdeg, h1, N);

    hipMemsetAsync(accum, 0, (size_t)N*64*4, stream);
    k_conv <<<64*WPC2, 256, 0, stream>>>(h1, Wb, elist, cellstart, basis, srcp, dstp, accum);
    k_final<<<N, 64, 0, stream>>>(accum, h1, rootb, biasb, invdeg, h2, N);

    k_knn_part <<<(Ny/256)*KCH, 256, 0, stream>>>(px4, posy, by, pd, pi, N, Ny);
    k_knn_merge<<<Ny/4, 256, 0, stream>>>(pd, pi, h2, (float*)d_out, Ny);
}

// Round 3
// 239.756 us; speedup vs baseline: 6.4505x; 2.5690x over previous
//
#include <hip/hip_runtime.h>
#include <hip/hip_bf16.h>
#include <math.h>

#define CDIV(a,b) (((a)+(b)-1)/(b))
#define WPCV 8    // workgroups per cell for conv (64*8 = 512 blocks)
#define KCH 8     // point chunks for knn phase 1

typedef __attribute__((ext_vector_type(8))) short bf16x8;
typedef __attribute__((ext_vector_type(4))) float f32x4;

__device__ __forceinline__ float elu_f(float x){ return x > 0.f ? x : expm1f(x); }
__device__ __forceinline__ unsigned short f2bf(float x){
    __hip_bfloat16 h = __float2bfloat16(x);
    union { __hip_bfloat16 b; unsigned short u; } cv; cv.b = h; return cv.u;
}
__device__ __forceinline__ float bf2f(unsigned short u){
    unsigned int ui = ((unsigned int)u) << 16;
    union { unsigned int u; float f; } cv; cv.u = ui; return cv.f;
}

// ---------------- basis + cell histogram + degree + rank ----------------
__global__ void k_basis(const float* __restrict__ ea, const int* __restrict__ dst,
                        float* __restrict__ basis, int* __restrict__ cellid,
                        int* __restrict__ cellcnt, int* __restrict__ deg,
                        int* __restrict__ rank, int E)
{
    __shared__ int hist[64];
    const int tid = threadIdx.x;
    if (tid < 64) hist[tid] = 0;
    __syncthreads();
    int e = blockIdx.x * blockDim.x + tid;
    if (e < E) {
        float f[3]; int bi[3];
        #pragma unroll
        for (int d = 0; d < 3; d++) {
            float v = ea[e*3+d] * 4.f;      // K-1 = 4
            float b = floorf(v);
            f[d] = v - b;
            int bb = (int)b; bb = bb < 0 ? 0 : (bb > 3 ? 3 : bb);
            bi[d] = bb;
        }
        int cell = bi[0] + 4*bi[1] + 16*bi[2];
        cellid[e] = cell;
        atomicAdd(&hist[cell], 1);
        rank[e] = atomicAdd(deg + dst[e], 1);
        float bs[8];
        #pragma unroll
        for (int c = 0; c < 8; c++) {
            float b = 1.f;
            #pragma unroll
            for (int d = 0; d < 3; d++)
                b *= ((c>>d)&1) ? f[d] : (1.f - f[d]);
            bs[c] = b;
        }
        float4* bw = (float4*)(basis + (size_t)e*8);
        bw[0] = make_float4(bs[0],bs[1],bs[2],bs[3]);
        bw[1] = make_float4(bs[4],bs[5],bs[6],bs[7]);
    }
    __syncthreads();
    if (tid < 64 && hist[tid]) atomicAdd(cellcnt + tid, hist[tid]);
}

__global__ void k_scan(const int* __restrict__ cnt, int* __restrict__ start, int* __restrict__ fill)
{
    if (threadIdx.x == 0 && blockIdx.x == 0) {
        int s = 0;
        for (int i = 0; i < 64; i++) { start[i] = s; fill[i] = s; s += cnt[i]; }
        start[64] = s;
    }
}

__global__ void k_scatter(const int* __restrict__ cellid, int* __restrict__ fill,
                          int* __restrict__ elist, int E)
{
    __shared__ int hist[64], bas[64];
    const int tid = threadIdx.x;
    if (tid < 64) hist[tid] = 0;
    __syncthreads();
    int e = blockIdx.x * blockDim.x + tid;
    int cell = 0, loc = 0;
    bool act = e < E;
    if (act) { cell = cellid[e]; loc = atomicAdd(&hist[cell], 1); }
    __syncthreads();
    if (tid < 64) bas[tid] = hist[tid] ? atomicAdd(fill + tid, hist[tid]) : 0;
    __syncthreads();
    if (act) elist[bas[cell] + loc] = e;
}

// ---------------- degree prefix scan (one block) + invdeg ----------------
__global__ __launch_bounds__(1024) void k_degscan(const int* __restrict__ deg,
                        int* __restrict__ csr, float* __restrict__ invdeg, int N)
{
    __shared__ int buf[2][1024];
    const int t = threadIdx.x;
    const int base = t*8;
    int loc[8]; int s = 0;
    #pragma unroll
    for (int j = 0; j < 8; j++) {
        loc[j] = s;
        int d = (base+j < N) ? deg[base+j] : 0;
        if (base+j < N) invdeg[base+j] = 1.f / fmaxf((float)d, 1.f);
        s += d;
    }
    buf[0][t] = s; __syncthreads();
    int pb = 0;
    for (int off = 1; off < 1024; off <<= 1) {
        int v = buf[pb][t];
        if (t >= off) v += buf[pb][t-off];
        buf[pb^1][t] = v; __syncthreads(); pb ^= 1;
    }
    int excl = buf[pb][t] - s;
    #pragma unroll
    for (int j = 0; j < 8; j++)
        if (base+j < N) csr[base+j] = excl + loc[j];
    if (t == 0) csr[N] = buf[pb][1023];
}

__global__ void k_eord(const int* __restrict__ dst, const int* __restrict__ rank,
                       const int* __restrict__ csr, int* __restrict__ eord, int E)
{
    int e = blockIdx.x * blockDim.x + threadIdx.x;
    if (e < E) eord[csr[dst[e]] + rank[e]] = e;
}

// ---------------- W prep: transpose + bf16 (WT[k][out][in]) ----------------
__global__ void k_wprep(const float* __restrict__ Wa, const float* __restrict__ Wb,
                        unsigned short* __restrict__ WTa, unsigned short* __restrict__ WTb)
{
    __shared__ float ws[64][65];
    const int b = blockIdx.x;
    const float* Wsrc = (b < 125) ? (Wa + (size_t)b*4096) : (Wb + (size_t)(b-125)*4096);
    unsigned short* Wdst = (b < 125) ? (WTa + (size_t)b*4096) : (WTb + (size_t)(b-125)*4096);
    const int tid = threadIdx.x;
    #pragma unroll
    for (int j = 0; j < 16; j++) {
        int idx = j*256 + tid;             // idx = i*64 + o
        ws[idx>>6][idx&63] = Wsrc[idx];
    }
    __syncthreads();
    #pragma unroll
    for (int j = 0; j < 16; j++) {
        int idx = j*256 + tid;             // idx = o*64 + i
        int o = idx>>6, i = idx&63;
        Wdst[idx] = f2bf(ws[i][o]);
    }
}

// ---------------- spline conv: MFMA, W8 resident in LDS, per-edge y out ----------------
// block = 256 (4 waves). Wave w: edge-half eh=w>>1 (32 edges), out-half oh=w&1 (32 outs).
// chunk = 64 edges. LDS: wt 64KB + xb 8KB + bts 2KB + eids.
__global__ __launch_bounds__(256) void k_conv(
    const float* __restrict__ xin, const unsigned short* __restrict__ WT,
    const int* __restrict__ elist, const int* __restrict__ cellstart,
    const float* __restrict__ basis, const int* __restrict__ src,
    unsigned short* __restrict__ ye)
{
    __shared__ unsigned short wt[8][64][64];   // [corner][out][in] bf16, row-swizzled
    __shared__ unsigned short xb[64][64];      // [edge][in] bf16, row-swizzled
    __shared__ float bts[8][64];               // [corner][edge]
    __shared__ int eids[64];

    const int cell = blockIdx.x / WPCV;
    const int sub  = blockIdx.x % WPCV;
    const int tid  = threadIdx.x;
    const int w    = tid >> 6;
    const int lane = tid & 63;
    const int eh   = w >> 1;       // edge half (0/1)
    const int oh   = w & 1;        // out half (0/1)
    const int l15  = lane & 15;
    const int kgrp = lane >> 4;    // 0..3
    const int swz  = lane & 7;     // row&7 for rows ≡ lane&15 (mod 16)

    int kc[8];
    {
        int b0 = cell & 3, b1 = (cell >> 2) & 3, b2 = (cell >> 4) & 3;
        #pragma unroll
        for (int c = 0; c < 8; c++)
            kc[c] = (b0 + (c&1)) + 5*(b1 + ((c>>1)&1)) + 25*(b2 + ((c>>2)&1));
    }

    // stage all 8 corner weight matrices (64KB), swizzled: chunk ^= row&7
    #pragma unroll
    for (int j = 0; j < 16; j++) {
        int cj  = j >> 1;
        int off = ((j & 1) << 8) + tid;        // 16B-chunk index within corner, 0..511
        int row = off >> 3, colc = off & 7;
        bf16x8 v = ((const bf16x8*)(WT + (size_t)kc[cj]*4096))[off];
        *(bf16x8*)&wt[cj][row][(colc ^ (row & 7)) << 3] = v;
    }

    const int s0 = cellstart[cell], s1 = cellstart[cell+1];
    const int se = tid >> 2, sm = tid & 3;

    for (int base = s0 + sub*64; base < s1; base += WPCV*64) {
        int ne = s1 - base; ne = ne > 64 ? 64 : ne;
        __syncthreads();   // prior chunk's readers done
        if (se < ne) {
            int eid = elist[base + se];
            int sn  = src[eid];
            const float4* xr = (const float4*)(xin + (size_t)sn*64);
            unsigned short tmp[16];
            #pragma unroll
            for (int j = 0; j < 4; j++) {
                float4 v = xr[sm*4 + j];
                tmp[j*4+0] = f2bf(v.x); tmp[j*4+1] = f2bf(v.y);
                tmp[j*4+2] = f2bf(v.z); tmp[j*4+3] = f2bf(v.w);
            }
            int c0 = (sm*2)     ^ (se & 7);
            int c1 = (sm*2 + 1) ^ (se & 7);
            *(bf16x8*)&xb[se][c0 << 3] = *(bf16x8*)&tmp[0];
            *(bf16x8*)&xb[se][c1 << 3] = *(bf16x8*)&tmp[8];
            if (sm == 0) {
                const float4* br = (const float4*)(basis + (size_t)eid*8);
                float4 bA = br[0], bB = br[1];
                bts[0][se]=bA.x; bts[1][se]=bA.y; bts[2][se]=bA.z; bts[3][se]=bA.w;
                bts[4][se]=bB.x; bts[5][se]=bB.y; bts[6][se]=bB.z; bts[7][se]=bB.w;
                eids[se] = eid;
            }
        } else if (sm == 0) {
            eids[se] = -1;
        }
        __syncthreads();

        // A fragments: rows eh*32 + me*16 + l15, k-chunk kh*4+kgrp
        bf16x8 a[2][2];
        #pragma unroll
        for (int me = 0; me < 2; me++) {
            int arow = eh*32 + me*16 + l15;
            #pragma unroll
            for (int kh = 0; kh < 2; kh++)
                a[me][kh] = *(const bf16x8*)&xb[arow][((kh*4 + kgrp) ^ swz) << 3];
        }

        f32x4 y[2][2] = {{{0,0,0,0},{0,0,0,0}},{{0,0,0,0},{0,0,0,0}}};
        #pragma unroll
        for (int c = 0; c < 8; c++) {
            float4 bv[2];
            bv[0] = *(const float4*)&bts[c][eh*32 +      (kgrp << 2)];
            bv[1] = *(const float4*)&bts[c][eh*32 + 16 + (kgrp << 2)];
            bf16x8 bfr[2][2];
            #pragma unroll
            for (int nb = 0; nb < 2; nb++) {
                int brow = oh*32 + nb*16 + l15;
                #pragma unroll
                for (int kh = 0; kh < 2; kh++)
                    bfr[nb][kh] = *(const bf16x8*)&wt[c][brow][((kh*4 + kgrp) ^ swz) << 3];
            }
            #pragma unroll
            for (int me = 0; me < 2; me++) {
                #pragma unroll
                for (int nb = 0; nb < 2; nb++) {
                    f32x4 t = {0.f, 0.f, 0.f, 0.f};
                    t = __builtin_amdgcn_mfma_f32_16x16x32_bf16(a[me][0], bfr[nb][0], t, 0, 0, 0);
                    t = __builtin_amdgcn_mfma_f32_16x16x32_bf16(a[me][1], bfr[nb][1], t, 0, 0, 0);
                    y[me][nb][0] = fmaf(bv[me].x, t[0], y[me][nb][0]);
                    y[me][nb][1] = fmaf(bv[me].y, t[1], y[me][nb][1]);
                    y[me][nb][2] = fmaf(bv[me].z, t[2], y[me][nb][2]);
                    y[me][nb][3] = fmaf(bv[me].w, t[3], y[me][nb][3]);
                }
            }
        }
        // store per-edge rows (C/D layout: col=l15, row=kgrp*4+r)
        #pragma unroll
        for (int me = 0; me < 2; me++) {
            #pragma unroll
            for (int r = 0; r < 4; r++) {
                int el  = eh*32 + me*16 + (kgrp << 2) + r;
                int eid = eids[el];
                if (eid >= 0) {
                    unsigned short* yp = ye + (size_t)eid*64 + oh*32 + l15;
                    yp[0]  = f2bf(y[me][0][r]);
                    yp[16] = f2bf(y[me][1][r]);
                }
            }
        }
    }
}

// ---------------- gather by dst: mean + root + bias + ELU ----------------
__global__ __launch_bounds__(256) void k_gather(
    const unsigned short* __restrict__ ye, const int* __restrict__ eord,
    const int* __restrict__ csr, const float* __restrict__ xin,
    const float* __restrict__ root, const float* __restrict__ bias,
    const float* __restrict__ invdeg, float* __restrict__ hout, int N)
{
    const int w = threadIdx.x >> 6, lane = threadIdx.x & 63;
    const int n = blockIdx.x*4 + w;
    if (n >= N) return;
    const int s0 = csr[n], s1 = csr[n+1];
    float acc0 = 0.f, acc1 = 0.f;
    int j = s0;
    for (; j + 1 < s1; j += 2) {
        int e0 = eord[j], e1 = eord[j+1];
        acc0 += bf2f(ye[(size_t)e0*64 + lane]);
        acc1 += bf2f(ye[(size_t)e1*64 + lane]);
    }
    if (j < s1) acc0 += bf2f(ye[(size_t)eord[j]*64 + lane]);
    float acc = (acc0 + acc1) * invdeg[n];
    float xv = xin[(size_t)n*64 + lane];
    float rt = bias[lane];
    #pragma unroll 8
    for (int i = 0; i < 64; i++)
        rt = fmaf(__shfl(xv, i, 64), root[i*64 + lane], rt);
    hout[(size_t)n*64 + lane] = elu_f(acc + rt);
}

// ---------------- pos_x preprocess ----------------
__global__ void k_px(const float* __restrict__ posx, const int* __restrict__ bx,
                     float4* __restrict__ px4, int N)
{
    int n = blockIdx.x * blockDim.x + threadIdx.x;
    if (n >= N) return;
    float off = (float)bx[n] * 1e5f;
    float a = posx[n*3+0]+off, b = posx[n*3+1]+off, c = posx[n*3+2]+off;
    px4[n] = make_float4(a, b, c, a*a + b*b + c*c);
}

// ---------------- 3-NN phase 1 ----------------
__global__ __launch_bounds__(256) void k_knn_part(
    const float4* __restrict__ px4, const float* __restrict__ posy,
    const int* __restrict__ by, float* __restrict__ pd, int* __restrict__ pi,
    int N, int Ny)
{
    __shared__ float4 pxs[1024];
    const int qb  = (blockIdx.x / KCH) * 256;
    const int ch  = blockIdx.x % KCH;
    const int NC  = N / KCH;                 // 1024
    const int tid = threadIdx.x;
    #pragma unroll
    for (int r = 0; r < 4; r++)
        pxs[tid + r*256] = px4[ch*NC + tid + r*256];
    const int q = qb + tid;
    float off = (float)by[q] * 1e5f;
    float qa = posy[q*3+0]+off, qbv = posy[q*3+1]+off, qc = posy[q*3+2]+off;
    float sy = qa*qa + qbv*qbv + qc*qc;
    __syncthreads();

    float td[3] = {3.4e38f, 3.4e38f, 3.4e38f};
    int   ti[3] = {0x7fffffff, 0x7fffffff, 0x7fffffff};
    #pragma unroll 4
    for (int p = 0; p < 1024; p++) {
        float4 pt = pxs[p];
        float d2 = sy + pt.w - 2.f*(qa*pt.x + qbv*pt.y + qc*pt.z);
        if (d2 < td[2]) {
            int gi = ch*NC + p;
            td[2] = d2; ti[2] = gi;
            if (td[2] < td[1]) { float tf=td[1]; td[1]=td[2]; td[2]=tf; int tt=ti[1]; ti[1]=ti[2]; ti[2]=tt; }
            if (td[1] < td[0]) { float tf=td[0]; td[0]=td[1]; td[1]=tf; int tt=ti[0]; ti[0]=ti[1]; ti[1]=tt; }
        }
    }
    size_t ob = ((size_t)q*KCH + ch)*3;
    pd[ob+0]=td[0]; pd[ob+1]=td[1]; pd[ob+2]=td[2];
    pi[ob+0]=ti[0]; pi[ob+1]=ti[1]; pi[ob+2]=ti[2];
}

// ---------------- 3-NN phase 2: merge + interpolate ----------------
__global__ __launch_bounds__(256) void k_knn_merge(
    const float* __restrict__ pd, const int* __restrict__ pi,
    const float* __restrict__ h2, float* __restrict__ out, int Ny)
{
    const int w = threadIdx.x >> 6, lane = threadIdx.x & 63;
    const int q = blockIdx.x*4 + w;
    float cd = 3.4e38f; int ci = 0x7fffffff;
    if (lane < 24) { cd = pd[(size_t)q*24 + lane]; ci = pi[(size_t)q*24 + lane]; }
    float rd[3]; int ri[3];
    #pragma unroll
    for (int j = 0; j < 3; j++) {
        float md = cd; int mi = ci;
        #pragma unroll
        for (int s = 1; s < 64; s <<= 1) {
            float od = __shfl_xor(md, s, 64);
            int   oi = __shfl_xor(mi, s, 64);
            if (od < md || (od == md && oi < mi)) { md = od; mi = oi; }
        }
        rd[j] = md; ri[j] = mi;
        if (ci == mi) { cd = 3.4e38f; ci = 0x7fffffff; }
    }
    float w0 = 1.f/fmaxf(rd[0], 1e-16f);
    float w1 = 1.f/fmaxf(rd[1], 1e-16f);
    float w2 = 1.f/fmaxf(rd[2], 1e-16f);
    float ws = w0 + w1 + w2;
    float v = w0*h2[(size_t)ri[0]*64+lane] + w1*h2[(size_t)ri[1]*64+lane]
            + w2*h2[(size_t)ri[2]*64+lane];
    out[(size_t)q*64+lane] = v / ws;
}

extern "C" void kernel_launch(void* const* d_in, const int* in_sizes, int n_in,
                              void* d_out, int out_size, void* d_ws, size_t ws_size,
                              hipStream_t stream)
{
    const float* x     = (const float*)d_in[0];
    const int*   ei    = (const int*)d_in[1];
    const float* ea    = (const float*)d_in[2];
    const float* posx  = (const float*)d_in[3];
    const int*   bx    = (const int*)d_in[4];
    const float* posy  = (const float*)d_in[5];
    const int*   by    = (const int*)d_in[6];
    const float* Wa    = (const float*)d_in[7];
    const float* roota = (const float*)d_in[8];
    const float* biasa = (const float*)d_in[9];
    const float* Wb    = (const float*)d_in[10];
    const float* rootb = (const float*)d_in[11];
    const float* biasb = (const float*)d_in[12];

    const int N  = in_sizes[0] / 64;
    const int E  = in_sizes[1] / 2;
    const int Ny = in_sizes[5] / 3;
    const int* srcp = ei;
    const int* dstp = ei + E;

    char* ws = (char*)d_ws;
    size_t off = 0;
    auto alloc = [&](size_t bytes) { void* p = ws + off; off += (bytes + 255) & ~255ull; return p; };
    float*  basis    = (float*)alloc((size_t)E*8*4);
    int*    cellid   = (int*)  alloc((size_t)E*4);
    int*    rank     = (int*)  alloc((size_t)E*4);
    int*    elist    = (int*)  alloc((size_t)E*4);
    int*    eord     = (int*)  alloc((size_t)E*4);
    int*    deg      = (int*)  alloc((size_t)N*4);
    int*    csr      = (int*)  alloc((size_t)(N+1)*4);
    float*  invdeg   = (float*)alloc((size_t)N*4);
    int*    cellcnt  = (int*)  alloc(64*4);
    int*    cellstart= (int*)  alloc(65*4);
    int*    cellfill = (int*)  alloc(64*4);
    float*  h1       = (float*)alloc((size_t)N*64*4);
    float*  h2       = (float*)alloc((size_t)N*64*4);
    float4* px4      = (float4*)alloc((size_t)N*16);
    unsigned short* WTa = (unsigned short*)alloc((size_t)125*4096*2);
    unsigned short* WTb = (unsigned short*)alloc((size_t)125*4096*2);
    unsigned short* ye  = (unsigned short*)alloc((size_t)E*64*2);
    // pd/pi alias ye (dead by the time knn runs)
    float* pd = (float*)ye;
    int*   pi = (int*)((char*)ye + ((size_t)8<<20));
    (void)ws_size; (void)n_in; (void)out_size;

    hipMemsetAsync(deg, 0, (size_t)N*4, stream);
    hipMemsetAsync(cellcnt, 0, 64*4, stream);

    k_basis  <<<CDIV(E,256), 256, 0, stream>>>(ea, dstp, basis, cellid, cellcnt, deg, rank, E);
    k_scan   <<<1, 64, 0, stream>>>(cellcnt, cellstart, cellfill);
    k_scatter<<<CDIV(E,256), 256, 0, stream>>>(cellid, cellfill, elist, E);
    k_degscan<<<1, 1024, 0, stream>>>(deg, csr, invdeg, N);
    k_eord   <<<CDIV(E,256), 256, 0, stream>>>(dstp, rank, csr, eord, E);
    k_wprep  <<<250, 256, 0, stream>>>(Wa, Wb, WTa, WTb);
    k_px     <<<CDIV(N,256), 256, 0, stream>>>(posx, bx, px4, N);

    k_conv  <<<64*WPCV, 256, 0, stream>>>(x, WTa, elist, cellstart, basis, srcp, ye);
    k_gather<<<CDIV(N,4), 256, 0, stream>>>(ye, eord, csr, x, roota, biasa, invdeg, h1, N);

    k_conv  <<<64*WPCV, 256, 0, stream>>>(h1, WTb, elist, cellstart, basis, srcp, ye);
    k_gather<<<CDIV(N,4), 256, 0, stream>>>(ye, eord, csr, h1, rootb, biasb, invdeg, h2, N);

    k_knn_part <<<(Ny/256)*KCH, 256, 0, stream>>>(px4, posy, by, pd, pi, N, Ny);
    k_knn_merge<<<Ny/4, 256, 0, stream>>>(pd, pi, h2, (float*)d_out, Ny);
}